// Round 7
// baseline (1152.294 us; speedup 1.0000x reference)
//
#include <hip/hip_runtime.h>
#include <math.h>

#define N_NODES 50000
#define E_EDGES 800000
#define HID 256
#define EPS_BN 1e-5f

typedef __attribute__((ext_vector_type(8))) short short8;            // bf16x8 MFMA frag
typedef __attribute__((ext_vector_type(4))) float floatx4;           // fp32x4 acc frag
typedef __attribute__((ext_vector_type(8))) unsigned short ushort8v; // bf16x8 mem

// ---------------------------------------------------------------------------
// bf16 helpers (RNE)
// ---------------------------------------------------------------------------
__device__ __forceinline__ unsigned short f2bf(float f) {
    unsigned u = __float_as_uint(f);
    u = (u + 0x7FFFu + ((u >> 16) & 1u)) >> 16;
    return (unsigned short)u;
}
__device__ __forceinline__ float bf2f(unsigned short b) {
    return __uint_as_float(((unsigned)b) << 16);
}

// ---------------------------------------------------------------------------
// Graph preprocessing
// ---------------------------------------------------------------------------
__global__ __launch_bounds__(256) void k_deg(const int* __restrict__ rows,
                                             int* __restrict__ deg) {
    int e = blockIdx.x * 256 + threadIdx.x;   // E_EDGES % 256 == 0
    atomicAdd(&deg[rows[e]], 1);
}

__global__ __launch_bounds__(256) void k_dinv(const int* __restrict__ deg,
                                              float* __restrict__ dinv) {
    int n = blockIdx.x * 256 + threadIdx.x;
    if (n < N_NODES) dinv[n] = rsqrtf((float)deg[n] + 1.0f);  // +1 self loop
}

// single-block exclusive scan of deg -> rowptr[0..N], shuffle-based
__global__ __launch_bounds__(1024) void k_scan(const int* __restrict__ deg,
                                               int* __restrict__ rowptr) {
    __shared__ int wsum[16];
    __shared__ int carry_s;
    int tid = threadIdx.x, lane = tid & 63, w = tid >> 6;
    if (tid == 0) carry_s = 0;
    __syncthreads();
    for (int base = 0; base < N_NODES; base += 1024) {
        int v = (base + tid < N_NODES) ? deg[base + tid] : 0;
        int x = v;
#pragma unroll
        for (int d = 1; d < 64; d <<= 1) {
            int t = __shfl_up(x, d);
            if (lane >= d) x += t;
        }
        if (lane == 63) wsum[w] = x;
        __syncthreads();
        if (w == 0) {
            int ws = (lane < 16) ? wsum[lane] : 0;
#pragma unroll
            for (int d = 1; d < 16; d <<= 1) {
                int t = __shfl_up(ws, d);
                if (lane >= d) ws += t;
            }
            if (lane < 16) wsum[lane] = ws;  // inclusive over waves
        }
        __syncthreads();
        int c = carry_s;
        int wbase = (w > 0) ? wsum[w - 1] : 0;
        if (base + tid < N_NODES) rowptr[base + tid] = c + wbase + x - v;
        __syncthreads();
        if (tid == 0) carry_s = c + wsum[15];
        __syncthreads();
    }
    if (threadIdx.x == 0) rowptr[N_NODES] = carry_s;
}

__global__ __launch_bounds__(256) void k_fill(const int* __restrict__ rows,
                                              const int* __restrict__ cols,
                                              const int* __restrict__ rowptr,
                                              int* __restrict__ cursor,
                                              int* __restrict__ colidx) {
    int e = blockIdx.x * 256 + threadIdx.x;
    int r = rows[e];
    int pos = atomicAdd(&cursor[r], 1);
    colidx[rowptr[r] + pos] = cols[e];
}

// ---------------------------------------------------------------------------
// fp32 -> bf16 conversions
// ---------------------------------------------------------------------------
__global__ __launch_bounds__(256) void k_f2bf_vec(const float* __restrict__ X,
                                                  unsigned short* __restrict__ Y,
                                                  int n4) {
    int i = blockIdx.x * 256 + threadIdx.x;
    if (i >= n4) return;
    float4 v = ((const float4*)X)[i];
    ushort4 o;
    o.x = f2bf(v.x); o.y = f2bf(v.y); o.z = f2bf(v.z); o.w = f2bf(v.w);
    ((ushort4*)Y)[i] = o;
}

// W: [K][HID] fp32 row-major  ->  Wt: [HID][K] bf16 (transposed)
__global__ __launch_bounds__(256) void k_wt(const float* __restrict__ W,
                                            unsigned short* __restrict__ Wt,
                                            int K) {
    int idx = blockIdx.x * 256 + threadIdx.x;
    if (idx >= K * HID) return;
    int k = idx >> 8;          // / HID
    int n = idx & (HID - 1);   // % HID
    Wt[(size_t)n * K + k] = f2bf(W[idx]);
}

// ---------------------------------------------------------------------------
// bf16 MFMA GEMM (m97 structure): C(bf16)[N x 256] = rowscale(.)*(A @ Bt^T)
//   A: dual-pointer concat along K. Bt: [256][K] bf16. 128x128 tile, 4 waves,
//   4x4 16x16x32 frags, BK=32, global_load_lds width=16 staging.
//   Optional fused BN column stats (sum, sumsq) from fp32 pre-round values.
// ---------------------------------------------------------------------------
__global__ __launch_bounds__(256) void k_gemm_mfma(
    const unsigned short* __restrict__ A0, int lda0,
    const unsigned short* __restrict__ A1, int lda1, int K0, int K,
    const unsigned short* __restrict__ Bt,
    unsigned short* __restrict__ C,
    const float* __restrict__ rowscale,
    float* __restrict__ stats)
{
    __shared__ alignas(16) unsigned short As[128 * 32];  // [row][k] 64B/row
    __shared__ alignas(16) unsigned short Bs[128 * 32];  // [n][k]   64B/row
    int tid = threadIdx.x;
    int wid = tid >> 6, lane = tid & 63;
    int row0 = blockIdx.x * 128;
    int n0 = blockIdx.y * 128;
    int wrow = (wid & 1) * 64, wcol = (wid >> 1) * 64;
    int lr = lane >> 2;            // staging: row within 16-row group
    int lk = (lane & 3) * 8;       // staging: element offset in k
    int qq = lane >> 4, mr = lane & 15;

    floatx4 acc[4][4];
#pragma unroll
    for (int i = 0; i < 4; ++i)
#pragma unroll
        for (int j = 0; j < 4; ++j) {
            floatx4 z = {0.f, 0.f, 0.f, 0.f};
            acc[i][j] = z;
        }

    for (int k0 = 0; k0 < K; k0 += 32) {
        const unsigned short* Abase;
        int lda;
        if (k0 < K0) { Abase = A0 + k0; lda = lda0; }
        else         { Abase = A1 + (k0 - K0); lda = lda1; }
#pragma unroll
        for (int i = 0; i < 2; ++i) {
            int rloc = wid * 32 + i * 16 + lr;
            int grow = row0 + rloc;
            if (grow > N_NODES - 1) grow = N_NODES - 1;  // clamp (stores guarded)
            const unsigned short* g = Abase + (size_t)grow * lda + lk;
            unsigned short* l = As + (wid * 32 + i * 16) * 32;
            __builtin_amdgcn_global_load_lds(
                (const __attribute__((address_space(1))) void*)g,
                (__attribute__((address_space(3))) void*)l, 16, 0, 0);
        }
#pragma unroll
        for (int i = 0; i < 2; ++i) {
            int nloc = wid * 32 + i * 16 + lr;
            const unsigned short* g = Bt + (size_t)(n0 + nloc) * K + k0 + lk;
            unsigned short* l = Bs + (wid * 32 + i * 16) * 32;
            __builtin_amdgcn_global_load_lds(
                (const __attribute__((address_space(1))) void*)g,
                (__attribute__((address_space(3))) void*)l, 16, 0, 0);
        }
        __syncthreads();
        short8 af[4], bfv[4];
#pragma unroll
        for (int i = 0; i < 4; ++i)
            af[i] = *(const short8*)(As + (wrow + i * 16 + mr) * 32 + qq * 8);
#pragma unroll
        for (int j = 0; j < 4; ++j)
            bfv[j] = *(const short8*)(Bs + (wcol + j * 16 + mr) * 32 + qq * 8);
#pragma unroll
        for (int i = 0; i < 4; ++i)
#pragma unroll
            for (int j = 0; j < 4; ++j)
                acc[i][j] = __builtin_amdgcn_mfma_f32_16x16x32_bf16(
                    af[i], bfv[j], acc[i][j], 0, 0, 0);
        __syncthreads();
    }

    // As is dead now; reuse as fp32 stats scratch (ls[128] sum, lq[128] sumsq)
    float* ls = (float*)As;
    float* lq = ((float*)As) + 128;
    if (stats) {
        ((float*)As)[tid] = 0.f;   // tid 0..255 zeros ls+lq
        __syncthreads();
    }

    // epilogue: C/D layout col=lane&15 (n), row=qq*4+reg (m-local); bf16 store
    float psum[4] = {0.f, 0.f, 0.f, 0.f};
    float psq[4]  = {0.f, 0.f, 0.f, 0.f};
#pragma unroll
    for (int i = 0; i < 4; ++i) {
        int rbase = row0 + wrow + i * 16 + qq * 4;
#pragma unroll
        for (int r = 0; r < 4; ++r) {
            int row = rbase + r;
            if (row >= N_NODES) continue;
            float rs = rowscale ? rowscale[row] : 1.0f;
            unsigned short* cp = C + (size_t)row * HID + n0 + wcol + mr;
#pragma unroll
            for (int j = 0; j < 4; ++j) {
                float v = acc[i][j][r] * rs;
                cp[j * 16] = f2bf(v);
                psum[j] += v;
                psq[j] += v * v;
            }
        }
    }
    if (stats) {
#pragma unroll
        for (int j = 0; j < 4; ++j) {
            int lc = wcol + j * 16 + mr;
            atomicAdd(&ls[lc], psum[j]);
            atomicAdd(&lq[lc], psq[j]);
        }
        __syncthreads();
        if (tid < 128) atomicAdd(&stats[n0 + tid], ls[tid]);
        else atomicAdd(&stats[HID + n0 + (tid - 128)], lq[tid - 128]);
    }
}

// ---------------------------------------------------------------------------
// GCN aggregation, bf16 in/out, fp32 accumulate, fused BN column stats.
// One wave per node per iteration (grid-stride); lane holds 4 channels
// (ushort4 = 8B gather/lane); colidx broadcast via full-wave shuffles.
// EXEC-SAFE: trip counts are wave-uniform; all 64 lanes stay active through
// every __shfl (the round-6 half-split divergence bug is structurally
// impossible here). 8-deep unroll for memory-level parallelism.
// ---------------------------------------------------------------------------
__global__ __launch_bounds__(256) void k_aggregate_bf(
    const unsigned short* __restrict__ g,   // [N][256] bf16 (dinv[col] pre-scaled)
    unsigned short* __restrict__ outp,      // [N][256] bf16
    const int* __restrict__ rowptr,
    const int* __restrict__ colidx,
    const float* __restrict__ dinv,
    float* __restrict__ stats) {
    int tid = threadIdx.x;
    int lane = tid & 63;
    int gw = blockIdx.x * 4 + (tid >> 6);
    int totw = gridDim.x * 4;
    float s0 = 0.f, s1 = 0.f, s2 = 0.f, s3 = 0.f;
    float q0 = 0.f, q1 = 0.f, q2 = 0.f, q3 = 0.f;
    for (int node = gw; node < N_NODES; node += totw) {
        int s = rowptr[node], e = rowptr[node + 1];
        ushort4 sv = ((const ushort4*)(g + (size_t)node * HID))[lane];  // self
        float a0 = bf2f(sv.x), a1 = bf2f(sv.y), a2 = bf2f(sv.z), a3 = bf2f(sv.w);
        for (int base = s; base < e; base += 64) {
            int cnt = e - base; if (cnt > 64) cnt = 64;
            int cidx = (lane < cnt) ? colidx[base + lane] : 0;
            int j = 0;
            for (; j + 8 <= cnt; j += 8) {
                int c0 = __shfl(cidx, j + 0), c1 = __shfl(cidx, j + 1);
                int c2 = __shfl(cidx, j + 2), c3 = __shfl(cidx, j + 3);
                int c4 = __shfl(cidx, j + 4), c5 = __shfl(cidx, j + 5);
                int c6 = __shfl(cidx, j + 6), c7 = __shfl(cidx, j + 7);
                ushort4 v0 = ((const ushort4*)(g + (size_t)c0 * HID))[lane];
                ushort4 v1 = ((const ushort4*)(g + (size_t)c1 * HID))[lane];
                ushort4 v2 = ((const ushort4*)(g + (size_t)c2 * HID))[lane];
                ushort4 v3 = ((const ushort4*)(g + (size_t)c3 * HID))[lane];
                ushort4 v4 = ((const ushort4*)(g + (size_t)c4 * HID))[lane];
                ushort4 v5 = ((const ushort4*)(g + (size_t)c5 * HID))[lane];
                ushort4 v6 = ((const ushort4*)(g + (size_t)c6 * HID))[lane];
                ushort4 v7 = ((const ushort4*)(g + (size_t)c7 * HID))[lane];
                a0 += ((bf2f(v0.x) + bf2f(v1.x)) + (bf2f(v2.x) + bf2f(v3.x))) +
                      ((bf2f(v4.x) + bf2f(v5.x)) + (bf2f(v6.x) + bf2f(v7.x)));
                a1 += ((bf2f(v0.y) + bf2f(v1.y)) + (bf2f(v2.y) + bf2f(v3.y))) +
                      ((bf2f(v4.y) + bf2f(v5.y)) + (bf2f(v6.y) + bf2f(v7.y)));
                a2 += ((bf2f(v0.z) + bf2f(v1.z)) + (bf2f(v2.z) + bf2f(v3.z))) +
                      ((bf2f(v4.z) + bf2f(v5.z)) + (bf2f(v6.z) + bf2f(v7.z)));
                a3 += ((bf2f(v0.w) + bf2f(v1.w)) + (bf2f(v2.w) + bf2f(v3.w))) +
                      ((bf2f(v4.w) + bf2f(v5.w)) + (bf2f(v6.w) + bf2f(v7.w)));
            }
            for (; j + 4 <= cnt; j += 4) {
                int c0 = __shfl(cidx, j + 0), c1 = __shfl(cidx, j + 1);
                int c2 = __shfl(cidx, j + 2), c3 = __shfl(cidx, j + 3);
                ushort4 v0 = ((const ushort4*)(g + (size_t)c0 * HID))[lane];
                ushort4 v1 = ((const ushort4*)(g + (size_t)c1 * HID))[lane];
                ushort4 v2 = ((const ushort4*)(g + (size_t)c2 * HID))[lane];
                ushort4 v3 = ((const ushort4*)(g + (size_t)c3 * HID))[lane];
                a0 += (bf2f(v0.x) + bf2f(v1.x)) + (bf2f(v2.x) + bf2f(v3.x));
                a1 += (bf2f(v0.y) + bf2f(v1.y)) + (bf2f(v2.y) + bf2f(v3.y));
                a2 += (bf2f(v0.z) + bf2f(v1.z)) + (bf2f(v2.z) + bf2f(v3.z));
                a3 += (bf2f(v0.w) + bf2f(v1.w)) + (bf2f(v2.w) + bf2f(v3.w));
            }
            for (; j < cnt; ++j) {
                int c = __shfl(cidx, j);
                ushort4 v = ((const ushort4*)(g + (size_t)c * HID))[lane];
                a0 += bf2f(v.x); a1 += bf2f(v.y); a2 += bf2f(v.z); a3 += bf2f(v.w);
            }
        }
        float rs = dinv[node];
        a0 *= rs; a1 *= rs; a2 *= rs; a3 *= rs;
        ushort4 o;
        o.x = f2bf(a0); o.y = f2bf(a1); o.z = f2bf(a2); o.w = f2bf(a3);
        ((ushort4*)(outp + (size_t)node * HID))[lane] = o;
        s0 += a0; s1 += a1; s2 += a2; s3 += a3;
        q0 += a0 * a0; q1 += a1 * a1; q2 += a2 * a2; q3 += a3 * a3;
    }
    // block reduce: 4 waves hold the same channel layout (ch = lane*4+k)
    __shared__ float ls[HID], lq[HID];
    ls[tid] = 0.f; lq[tid] = 0.f;
    __syncthreads();
    atomicAdd(&ls[lane * 4 + 0], s0); atomicAdd(&lq[lane * 4 + 0], q0);
    atomicAdd(&ls[lane * 4 + 1], s1); atomicAdd(&lq[lane * 4 + 1], q1);
    atomicAdd(&ls[lane * 4 + 2], s2); atomicAdd(&lq[lane * 4 + 2], q2);
    atomicAdd(&ls[lane * 4 + 3], s3); atomicAdd(&lq[lane * 4 + 3], q3);
    __syncthreads();
    atomicAdd(&stats[tid], ls[tid]);
    atomicAdd(&stats[HID + tid], lq[tid]);
}

// ---------------------------------------------------------------------------
// BatchNorm finalize + apply
// ---------------------------------------------------------------------------
__global__ __launch_bounds__(256) void k_bnfinal(const float* __restrict__ stats,
                                                 const float* __restrict__ gamma,
                                                 const float* __restrict__ beta,
                                                 float* __restrict__ scsh) {
    int ch = threadIdx.x;
    const float invn = 1.0f / (float)N_NODES;
    float mean = stats[ch] * invn;
    float var = stats[HID + ch] * invn - mean * mean;
    var = fmaxf(var, 0.f);
    float sc = gamma[ch] * rsqrtf(var + EPS_BN);
    scsh[ch] = sc;
    scsh[HID + ch] = beta[ch] - mean * sc;
}

__global__ __launch_bounds__(256) void k_bnapply_bf(const unsigned short* __restrict__ X,
                                                    unsigned short* __restrict__ Y,
                                                    const float* __restrict__ scsh) {
    int i = blockIdx.x * 256 + threadIdx.x;  // over N*32 ushort8 groups (exact)
    int ch8 = (i & 31) * 8;
    ushort8v v = *(const ushort8v*)(X + (size_t)i * 8);
    ushort8v o;
#pragma unroll
    for (int k = 0; k < 8; ++k) {
        float f = bf2f((unsigned short)v[k]);
        o[k] = f2bf(fmaxf(f * scsh[ch8 + k] + scsh[HID + ch8 + k], 0.f));
    }
    *(ushort8v*)(Y + (size_t)i * 8) = o;
}

// ---------------------------------------------------------------------------
// Head: optional fused BN (scsh != null: v = relu(sc*v+sh)) then
// logits = v @ W(256x2 fp32) + b, log_softmax. One wave per row.
// ---------------------------------------------------------------------------
__global__ __launch_bounds__(256) void k_head_bf(const unsigned short* __restrict__ H,
                                                 const float* __restrict__ scsh,
                                                 const float* __restrict__ W,
                                                 const float* __restrict__ b,
                                                 float* __restrict__ outp) {
    int wave = (blockIdx.x * 256 + threadIdx.x) >> 6;
    int lane = threadIdx.x & 63;
    if (wave >= N_NODES) return;
    ushort4 h4 = ((const ushort4*)(H + (size_t)wave * HID))[lane];
    float h0 = bf2f(h4.x), h1 = bf2f(h4.y), h2 = bf2f(h4.z), h3 = bf2f(h4.w);
    if (scsh) {
        int ch = lane * 4;
        h0 = fmaxf(h0 * scsh[ch + 0] + scsh[HID + ch + 0], 0.f);
        h1 = fmaxf(h1 * scsh[ch + 1] + scsh[HID + ch + 1], 0.f);
        h2 = fmaxf(h2 * scsh[ch + 2] + scsh[HID + ch + 2], 0.f);
        h3 = fmaxf(h3 * scsh[ch + 3] + scsh[HID + ch + 3], 0.f);
    }
    const float2* W2 = (const float2*)W;
    float2 w0 = W2[lane * 4 + 0], w1 = W2[lane * 4 + 1];
    float2 w2 = W2[lane * 4 + 2], w3 = W2[lane * 4 + 3];
    float p0 = h0 * w0.x + h1 * w1.x + h2 * w2.x + h3 * w3.x;
    float p1 = h0 * w0.y + h1 * w1.y + h2 * w2.y + h3 * w3.y;
    for (int off = 32; off > 0; off >>= 1) {
        p0 += __shfl_down(p0, off);
        p1 += __shfl_down(p1, off);
    }
    if (lane == 0) {
        float z0 = p0 + b[0], z1 = p1 + b[1];
        float m = fmaxf(z0, z1);
        float lse = m + logf(expf(z0 - m) + expf(z1 - m));
        outp[(size_t)wave * 2 + 0] = z0 - lse;
        outp[(size_t)wave * 2 + 1] = z1 - lse;
    }
}

// ---------------------------------------------------------------------------
extern "C" void kernel_launch(void* const* d_in, const int* in_sizes, int n_in,
                              void* d_out, int out_size, void* d_ws, size_t ws_size,
                              hipStream_t stream) {
    const float* x       = (const float*)d_in[0];      // N x 512
    const int*   ei      = (const int*)d_in[1];        // 2 x E (rows, cols)
    const float* conv_w0 = (const float*)d_in[2];      // 512 x 256
    const float* conv_ws = (const float*)d_in[3];      // 2 x 256 x 256
    const float* bn_g    = (const float*)d_in[5];
    const float* bn_b    = (const float*)d_in[6];
    const float* fcg_w0  = (const float*)d_in[7];      // 256 x 256
    const float* fcg_ws  = (const float*)d_in[8];      // 2 x 512 x 256
    const float* bng_g   = (const float*)d_in[10];
    const float* bng_b   = (const float*)d_in[11];
    const float* fcl_w   = (const float*)d_in[12];     // 3 x 256 x 256
    const float* bnl_g   = (const float*)d_in[14];
    const float* bnl_b   = (const float*)d_in[15];
    const float* outg_w  = (const float*)d_in[16];     // 256 x 2
    const float* outg_b  = (const float*)d_in[17];
    const float* outl_w  = (const float*)d_in[18];     // 3 x 256 x 2
    const float* outl_b  = (const float*)d_in[19];     // 3 x 2
    float* out = (float*)d_out;                        // (4, N, 2)

    const int* rows = ei;
    const int* cols = ei + E_EDGES;

    // workspace carve
    char* ws = (char*)d_ws;
    size_t off = 0;
    auto carve = [&](size_t bytes) -> void* {
        void* p = ws + off;
        off = (off + bytes + 255) & ~(size_t)255;
        return p;
    };
    const size_t ACT = (size_t)N_NODES * HID * 2;  // 25.6 MB bf16 activation
    unsigned short* xbf = (unsigned short*)carve((size_t)N_NODES * 512 * 2);
    unsigned short* tG  = (unsigned short*)carve(ACT);  // GEMM out
    unsigned short* tA  = (unsigned short*)carve(ACT);  // aggregate out
    unsigned short* hbf = (unsigned short*)carve(ACT);  // h_gcn
    unsigned short* g1  = (unsigned short*)carve(ACT);  // hg ping
    unsigned short* g2  = (unsigned short*)carve(ACT);  // hg pong
    unsigned short* wt_conv0 = (unsigned short*)carve(256 * 512 * 2);
    unsigned short* wt_conv1 = (unsigned short*)carve(256 * 256 * 2);
    unsigned short* wt_conv2 = (unsigned short*)carve(256 * 256 * 2);
    unsigned short* wt_fcg0  = (unsigned short*)carve(256 * 256 * 2);
    unsigned short* wt_fcgs0 = (unsigned short*)carve(256 * 512 * 2);
    unsigned short* wt_fcgs1 = (unsigned short*)carve(256 * 512 * 2);
    unsigned short* wt_fcl0  = (unsigned short*)carve(256 * 256 * 2);
    unsigned short* wt_fcl1  = (unsigned short*)carve(256 * 256 * 2);
    unsigned short* wt_fcl2  = (unsigned short*)carve(256 * 256 * 2);
    int*   deg    = (int*)carve(2 * 50048 * 4);  // deg + cursor (one memset)
    int*   cursor = deg + 50048;
    int*   rowptr = (int*)carve((size_t)(N_NODES + 1) * 4);
    float* dinv   = (float*)carve((size_t)N_NODES * 4);
    int*   colidx = (int*)carve((size_t)E_EDGES * 4);
    float* stats_all = (float*)carve(9 * 2 * HID * 4);  // 9 layers x (sum,sumsq)
    float* scsh   = (float*)carve(2 * HID * 4);
    (void)off; (void)ws_size; (void)in_sizes; (void)n_in; (void)out_size;

    // --- graph prep + stat zeroing ---
    hipMemsetAsync(deg, 0, 2 * 50048 * 4, stream);
    hipMemsetAsync(stats_all, 0, 9 * 2 * HID * 4, stream);
    k_deg<<<E_EDGES / 256, 256, 0, stream>>>(rows, deg);
    k_dinv<<<(N_NODES + 255) / 256, 256, 0, stream>>>(deg, dinv);
    k_scan<<<1, 1024, 0, stream>>>(deg, rowptr);
    k_fill<<<E_EDGES / 256, 256, 0, stream>>>(rows, cols, rowptr, cursor, colidx);

    // --- dtype prep ---
    k_f2bf_vec<<<(N_NODES * 512 / 4 + 255) / 256, 256, 0, stream>>>(x, xbf, N_NODES * 512 / 4);
    k_wt<<<(512 * 256 + 255) / 256, 256, 0, stream>>>(conv_w0, wt_conv0, 512);
    k_wt<<<(256 * 256 + 255) / 256, 256, 0, stream>>>(conv_ws, wt_conv1, 256);
    k_wt<<<(256 * 256 + 255) / 256, 256, 0, stream>>>(conv_ws + 65536, wt_conv2, 256);
    k_wt<<<(256 * 256 + 255) / 256, 256, 0, stream>>>(fcg_w0, wt_fcg0, 256);
    k_wt<<<(512 * 256 + 255) / 256, 256, 0, stream>>>(fcg_ws, wt_fcgs0, 512);
    k_wt<<<(512 * 256 + 255) / 256, 256, 0, stream>>>(fcg_ws + 131072, wt_fcgs1, 512);
    k_wt<<<(256 * 256 + 255) / 256, 256, 0, stream>>>(fcl_w, wt_fcl0, 256);
    k_wt<<<(256 * 256 + 255) / 256, 256, 0, stream>>>(fcl_w + 65536, wt_fcl1, 256);
    k_wt<<<(256 * 256 + 255) / 256, 256, 0, stream>>>(fcl_w + 131072, wt_fcl2, 256);

    dim3 ggrid((N_NODES + 127) / 128, 2);
    auto gemm = [&](const unsigned short* A0, int lda0,
                    const unsigned short* A1, int lda1, int K0, int K,
                    const unsigned short* Bt, unsigned short* C,
                    const float* rs, float* st) {
        k_gemm_mfma<<<ggrid, 256, 0, stream>>>(A0, lda0, A1, lda1, K0, K, Bt, C, rs, st);
    };
    auto bnfin = [&](float* st, const unsigned short* X, unsigned short* Y,
                     const float* gamma, const float* beta) {
        k_bnfinal<<<1, 256, 0, stream>>>(st, gamma, beta, scsh);
        k_bnapply_bf<<<N_NODES * 32 / 256, 256, 0, stream>>>(X, Y, scsh);
    };
    auto agg = [&](const unsigned short* in, unsigned short* outb, float* st) {
        k_aggregate_bf<<<2048, 256, 0, stream>>>(in, outb, rowptr, colidx, dinv, st);
    };
    float* st;

    // --- GCN layer 0 (K=512) ---
    st = stats_all + 0 * 512;
    gemm(xbf, 512, nullptr, 0, 512, 512, wt_conv0, tG, dinv, nullptr);
    agg(tG, tA, st);
    bnfin(st, tA, g1, bn_g + 0, bn_b + 0);          // h1
    // --- GCN layer 1 ---
    st = stats_all + 1 * 512;
    gemm(g1, 256, nullptr, 0, 256, 256, wt_conv1, tG, dinv, nullptr);
    agg(tG, tA, st);
    bnfin(st, tA, g2, bn_g + 256, bn_b + 256);      // h2
    // --- GCN layer 2 ---
    st = stats_all + 2 * 512;
    gemm(g2, 256, nullptr, 0, 256, 256, wt_conv2, tG, dinv, nullptr);
    agg(tG, tA, st);
    bnfin(st, tA, hbf, bn_g + 512, bn_b + 512);     // h_gcn

    // --- global path level 0 ---
    st = stats_all + 3 * 512;
    gemm(hbf, 256, nullptr, 0, 256, 256, wt_fcg0, tG, nullptr, st);
    bnfin(st, tG, g1, bng_g + 0, bng_b + 0);        // hg0
    // local head 0 (BN fused into head)
    st = stats_all + 4 * 512;
    gemm(g1, 256, nullptr, 0, 256, 256, wt_fcl0, tG, nullptr, st);
    k_bnfinal<<<1, 256, 0, stream>>>(st, bnl_g + 0, bnl_b + 0, scsh);
    k_head_bf<<<N_NODES / 4, 256, 0, stream>>>(tG, scsh, outl_w, outl_b,
                                               out + (size_t)1 * N_NODES * 2);
    // --- level 1: xg1 = concat(hg0, h) @ fcg_ws[0]  (dual-A, K=512) ---
    st = stats_all + 5 * 512;
    gemm(g1, 256, hbf, 256, 256, 512, wt_fcgs0, tG, nullptr, st);
    bnfin(st, tG, g2, bng_g + 256, bng_b + 256);    // hg1
    // local head 1 (BN fused into head)
    st = stats_all + 6 * 512;
    gemm(g2, 256, nullptr, 0, 256, 256, wt_fcl1, tG, nullptr, st);
    k_bnfinal<<<1, 256, 0, stream>>>(st, bnl_g + 256, bnl_b + 256, scsh);
    k_head_bf<<<N_NODES / 4, 256, 0, stream>>>(tG, scsh, outl_w + 512, outl_b + 2,
                                               out + (size_t)2 * N_NODES * 2);
    // --- level 2: xg2 = concat(hg1, h) @ fcg_ws[1] ---
    st = stats_all + 7 * 512;
    gemm(g2, 256, hbf, 256, 256, 512, wt_fcgs1, tG, nullptr, st);
    bnfin(st, tG, g1, bng_g + 512, bng_b + 512);    // hg2
    // local head 2 (BN fused into head)
    st = stats_all + 8 * 512;
    gemm(g1, 256, nullptr, 0, 256, 256, wt_fcl2, tG, nullptr, st);
    k_bnfinal<<<1, 256, 0, stream>>>(st, bnl_g + 512, bnl_b + 512, scsh);
    k_head_bf<<<N_NODES / 4, 256, 0, stream>>>(tG, scsh, outl_w + 1024, outl_b + 4,
                                               out + (size_t)3 * N_NODES * 2);
    // global head (og) from hg2 (already BN-applied)
    k_head_bf<<<N_NODES / 4, 256, 0, stream>>>(g1, nullptr, outg_w, outg_b, out);
}

// Round 8
// 1071.847 us; speedup vs baseline: 1.0751x; 1.0751x over previous
//
#include <hip/hip_runtime.h>
#include <math.h>

#define N_NODES 50000
#define E_EDGES 800000
#define HID 256
#define EPS_BN 1e-5f

typedef __attribute__((ext_vector_type(8))) short short8;            // bf16x8 MFMA frag
typedef __attribute__((ext_vector_type(4))) float floatx4;           // fp32x4 acc frag
typedef __attribute__((ext_vector_type(8))) unsigned short ushort8v; // bf16x8 mem

// ---------------------------------------------------------------------------
// bf16 helpers (RNE)
// ---------------------------------------------------------------------------
__device__ __forceinline__ unsigned short f2bf(float f) {
    unsigned u = __float_as_uint(f);
    u = (u + 0x7FFFu + ((u >> 16) & 1u)) >> 16;
    return (unsigned short)u;
}
__device__ __forceinline__ float bf2f(unsigned short b) {
    return __uint_as_float(((unsigned)b) << 16);
}
// BN scale/shift from raw stats (sum, sumsq) + gamma/beta
__device__ __forceinline__ void bn_scsh(const float* stats, const float* gamma,
                                        const float* beta, int ch,
                                        float& sc, float& sh) {
    const float invn = 1.0f / (float)N_NODES;
    float mean = stats[ch] * invn;
    float var = stats[HID + ch] * invn - mean * mean;
    var = fmaxf(var, 0.f);
    sc = gamma[ch] * rsqrtf(var + EPS_BN);
    sh = beta[ch] - mean * sc;
}

// ---------------------------------------------------------------------------
// Graph preprocessing
// ---------------------------------------------------------------------------
__global__ __launch_bounds__(256) void k_deg(const int* __restrict__ rows,
                                             int* __restrict__ deg) {
    int e = blockIdx.x * 256 + threadIdx.x;   // E_EDGES % 256 == 0
    atomicAdd(&deg[rows[e]], 1);
}

__global__ __launch_bounds__(256) void k_dinv(const int* __restrict__ deg,
                                              float* __restrict__ dinv) {
    int n = blockIdx.x * 256 + threadIdx.x;
    if (n < N_NODES) dinv[n] = rsqrtf((float)deg[n] + 1.0f);  // +1 self loop
}

// single-block exclusive scan of deg -> rowptr[0..N], shuffle-based
__global__ __launch_bounds__(1024) void k_scan(const int* __restrict__ deg,
                                               int* __restrict__ rowptr) {
    __shared__ int wsum[16];
    __shared__ int carry_s;
    int tid = threadIdx.x, lane = tid & 63, w = tid >> 6;
    if (tid == 0) carry_s = 0;
    __syncthreads();
    for (int base = 0; base < N_NODES; base += 1024) {
        int v = (base + tid < N_NODES) ? deg[base + tid] : 0;
        int x = v;
#pragma unroll
        for (int d = 1; d < 64; d <<= 1) {
            int t = __shfl_up(x, d);
            if (lane >= d) x += t;
        }
        if (lane == 63) wsum[w] = x;
        __syncthreads();
        if (w == 0) {
            int ws = (lane < 16) ? wsum[lane] : 0;
#pragma unroll
            for (int d = 1; d < 16; d <<= 1) {
                int t = __shfl_up(ws, d);
                if (lane >= d) ws += t;
            }
            if (lane < 16) wsum[lane] = ws;  // inclusive over waves
        }
        __syncthreads();
        int c = carry_s;
        int wbase = (w > 0) ? wsum[w - 1] : 0;
        if (base + tid < N_NODES) rowptr[base + tid] = c + wbase + x - v;
        __syncthreads();
        if (tid == 0) carry_s = c + wsum[15];
        __syncthreads();
    }
    if (threadIdx.x == 0) rowptr[N_NODES] = carry_s;
}

__global__ __launch_bounds__(256) void k_fill(const int* __restrict__ rows,
                                              const int* __restrict__ cols,
                                              const int* __restrict__ rowptr,
                                              int* __restrict__ cursor,
                                              int* __restrict__ colidx) {
    int e = blockIdx.x * 256 + threadIdx.x;
    int r = rows[e];
    int pos = atomicAdd(&cursor[r], 1);
    colidx[rowptr[r] + pos] = cols[e];
}

// ---------------------------------------------------------------------------
// fp32 -> bf16 conversions
// ---------------------------------------------------------------------------
__global__ __launch_bounds__(256) void k_f2bf_vec(const float* __restrict__ X,
                                                  unsigned short* __restrict__ Y,
                                                  int n4) {
    int i = blockIdx.x * 256 + threadIdx.x;
    if (i >= n4) return;
    float4 v = ((const float4*)X)[i];
    ushort4 o;
    o.x = f2bf(v.x); o.y = f2bf(v.y); o.z = f2bf(v.z); o.w = f2bf(v.w);
    ((ushort4*)Y)[i] = o;
}

// W: [K][HID] fp32 row-major  ->  Wt: [HID][K] bf16 (transposed)
__global__ __launch_bounds__(256) void k_wt(const float* __restrict__ W,
                                            unsigned short* __restrict__ Wt,
                                            int K) {
    int idx = blockIdx.x * 256 + threadIdx.x;
    if (idx >= K * HID) return;
    int k = idx >> 8;          // / HID
    int n = idx & (HID - 1);   // % HID
    Wt[(size_t)n * K + k] = f2bf(W[idx]);
}

// ---------------------------------------------------------------------------
// bf16 MFMA GEMM (m97 structure): C(bf16)[N x 256] = rowscale(.)*(A @ Bt^T)
//   A: dual-pointer concat along K. Bt: [256][K] bf16. 128x128 tile, 4 waves,
//   4x4 16x16x32 frags, BK=32, global_load_lds width=16 staging.
//   Optional fused BN column stats (sum, sumsq) from fp32 pre-round values.
// ---------------------------------------------------------------------------
__global__ __launch_bounds__(256) void k_gemm_mfma(
    const unsigned short* __restrict__ A0, int lda0,
    const unsigned short* __restrict__ A1, int lda1, int K0, int K,
    const unsigned short* __restrict__ Bt,
    unsigned short* __restrict__ C,
    const float* __restrict__ rowscale,
    float* __restrict__ stats)
{
    __shared__ alignas(16) unsigned short As[128 * 32];  // [row][k] 64B/row
    __shared__ alignas(16) unsigned short Bs[128 * 32];  // [n][k]   64B/row
    int tid = threadIdx.x;
    int wid = tid >> 6, lane = tid & 63;
    int row0 = blockIdx.x * 128;
    int n0 = blockIdx.y * 128;
    int wrow = (wid & 1) * 64, wcol = (wid >> 1) * 64;
    int lr = lane >> 2;            // staging: row within 16-row group
    int lk = (lane & 3) * 8;       // staging: element offset in k
    int qq = lane >> 4, mr = lane & 15;

    floatx4 acc[4][4];
#pragma unroll
    for (int i = 0; i < 4; ++i)
#pragma unroll
        for (int j = 0; j < 4; ++j) {
            floatx4 z = {0.f, 0.f, 0.f, 0.f};
            acc[i][j] = z;
        }

    for (int k0 = 0; k0 < K; k0 += 32) {
        const unsigned short* Abase;
        int lda;
        if (k0 < K0) { Abase = A0 + k0; lda = lda0; }
        else         { Abase = A1 + (k0 - K0); lda = lda1; }
#pragma unroll
        for (int i = 0; i < 2; ++i) {
            int rloc = wid * 32 + i * 16 + lr;
            int grow = row0 + rloc;
            if (grow > N_NODES - 1) grow = N_NODES - 1;  // clamp (stores guarded)
            const unsigned short* g = Abase + (size_t)grow * lda + lk;
            unsigned short* l = As + (wid * 32 + i * 16) * 32;
            __builtin_amdgcn_global_load_lds(
                (const __attribute__((address_space(1))) void*)g,
                (__attribute__((address_space(3))) void*)l, 16, 0, 0);
        }
#pragma unroll
        for (int i = 0; i < 2; ++i) {
            int nloc = wid * 32 + i * 16 + lr;
            const unsigned short* g = Bt + (size_t)(n0 + nloc) * K + k0 + lk;
            unsigned short* l = Bs + (wid * 32 + i * 16) * 32;
            __builtin_amdgcn_global_load_lds(
                (const __attribute__((address_space(1))) void*)g,
                (__attribute__((address_space(3))) void*)l, 16, 0, 0);
        }
        __syncthreads();
        short8 af[4], bfv[4];
#pragma unroll
        for (int i = 0; i < 4; ++i)
            af[i] = *(const short8*)(As + (wrow + i * 16 + mr) * 32 + qq * 8);
#pragma unroll
        for (int j = 0; j < 4; ++j)
            bfv[j] = *(const short8*)(Bs + (wcol + j * 16 + mr) * 32 + qq * 8);
#pragma unroll
        for (int i = 0; i < 4; ++i)
#pragma unroll
            for (int j = 0; j < 4; ++j)
                acc[i][j] = __builtin_amdgcn_mfma_f32_16x16x32_bf16(
                    af[i], bfv[j], acc[i][j], 0, 0, 0);
        __syncthreads();
    }

    // As is dead now; reuse as fp32 stats scratch (ls[128] sum, lq[128] sumsq)
    float* ls = (float*)As;
    float* lq = ((float*)As) + 128;
    if (stats) {
        ((float*)As)[tid] = 0.f;   // tid 0..255 zeros ls+lq
        __syncthreads();
    }

    // epilogue: C/D layout col=lane&15 (n), row=qq*4+reg (m-local); bf16 store
    float psum[4] = {0.f, 0.f, 0.f, 0.f};
    float psq[4]  = {0.f, 0.f, 0.f, 0.f};
#pragma unroll
    for (int i = 0; i < 4; ++i) {
        int rbase = row0 + wrow + i * 16 + qq * 4;
#pragma unroll
        for (int r = 0; r < 4; ++r) {
            int row = rbase + r;
            if (row >= N_NODES) continue;
            float rs = rowscale ? rowscale[row] : 1.0f;
            unsigned short* cp = C + (size_t)row * HID + n0 + wcol + mr;
#pragma unroll
            for (int j = 0; j < 4; ++j) {
                float v = acc[i][j][r] * rs;
                cp[j * 16] = f2bf(v);
                psum[j] += v;
                psq[j] += v * v;
            }
        }
    }
    if (stats) {
#pragma unroll
        for (int j = 0; j < 4; ++j) {
            int lc = wcol + j * 16 + mr;
            atomicAdd(&ls[lc], psum[j]);
            atomicAdd(&lq[lc], psq[j]);
        }
        __syncthreads();
        if (tid < 128) atomicAdd(&stats[n0 + tid], ls[tid]);
        else atomicAdd(&stats[HID + n0 + (tid - 128)], lq[tid - 128]);
    }
}

// ---------------------------------------------------------------------------
// GCN aggregation, bf16 in/out, fp32 accumulate, fused BN column stats.
// ROUND-4 CONFIG (measured best: 87 µs @ 782 blocks; 2048-block variants
// regressed to 103-113 µs — L2 thrash + stats-atomic tail scale with grid).
// One wave per node per iteration; lane holds 4 channels (ushort4 = 8B
// gather/lane); colidx broadcast via full-wave shuffles (exec-safe).
// ---------------------------------------------------------------------------
__global__ __launch_bounds__(256) void k_aggregate_bf(
    const unsigned short* __restrict__ g,   // [N][256] bf16 (dinv[col] pre-scaled)
    unsigned short* __restrict__ outp,      // [N][256] bf16
    const int* __restrict__ rowptr,
    const int* __restrict__ colidx,
    const float* __restrict__ dinv,
    float* __restrict__ stats) {
    int lane = threadIdx.x & 63;
    int gw = blockIdx.x * 4 + (threadIdx.x >> 6);
    int totw = gridDim.x * 4;
    float s0 = 0.f, s1 = 0.f, s2 = 0.f, s3 = 0.f;
    float q0 = 0.f, q1 = 0.f, q2 = 0.f, q3 = 0.f;
    for (int node = gw; node < N_NODES; node += totw) {
        int s = rowptr[node], e = rowptr[node + 1];
        ushort4 sv = ((const ushort4*)(g + (size_t)node * HID))[lane];  // self
        float a0 = bf2f(sv.x), a1 = bf2f(sv.y), a2 = bf2f(sv.z), a3 = bf2f(sv.w);
        for (int base = s; base < e; base += 64) {
            int cnt = e - base; if (cnt > 64) cnt = 64;
            int cidx = (lane < cnt) ? colidx[base + lane] : 0;
            int j = 0;
            for (; j + 4 <= cnt; j += 4) {
                int c0 = __shfl(cidx, j + 0), c1 = __shfl(cidx, j + 1);
                int c2 = __shfl(cidx, j + 2), c3 = __shfl(cidx, j + 3);
                ushort4 v0 = ((const ushort4*)(g + (size_t)c0 * HID))[lane];
                ushort4 v1 = ((const ushort4*)(g + (size_t)c1 * HID))[lane];
                ushort4 v2 = ((const ushort4*)(g + (size_t)c2 * HID))[lane];
                ushort4 v3 = ((const ushort4*)(g + (size_t)c3 * HID))[lane];
                a0 += (bf2f(v0.x) + bf2f(v1.x)) + (bf2f(v2.x) + bf2f(v3.x));
                a1 += (bf2f(v0.y) + bf2f(v1.y)) + (bf2f(v2.y) + bf2f(v3.y));
                a2 += (bf2f(v0.z) + bf2f(v1.z)) + (bf2f(v2.z) + bf2f(v3.z));
                a3 += (bf2f(v0.w) + bf2f(v1.w)) + (bf2f(v2.w) + bf2f(v3.w));
            }
            for (; j < cnt; ++j) {
                int c = __shfl(cidx, j);
                ushort4 v = ((const ushort4*)(g + (size_t)c * HID))[lane];
                a0 += bf2f(v.x); a1 += bf2f(v.y); a2 += bf2f(v.z); a3 += bf2f(v.w);
            }
        }
        float rs = dinv[node];
        a0 *= rs; a1 *= rs; a2 *= rs; a3 *= rs;
        ushort4 o;
        o.x = f2bf(a0); o.y = f2bf(a1); o.z = f2bf(a2); o.w = f2bf(a3);
        ((ushort4*)(outp + (size_t)node * HID))[lane] = o;
        s0 += a0; s1 += a1; s2 += a2; s3 += a3;
        q0 += a0 * a0; q1 += a1 * a1; q2 += a2 * a2; q3 += a3 * a3;
    }
    // block reduce: 4 waves hold the same channel layout (ch = lane*4+k)
    __shared__ float ls[HID], lq[HID];
    ls[threadIdx.x] = 0.f; lq[threadIdx.x] = 0.f;
    __syncthreads();
    atomicAdd(&ls[lane * 4 + 0], s0); atomicAdd(&lq[lane * 4 + 0], q0);
    atomicAdd(&ls[lane * 4 + 1], s1); atomicAdd(&lq[lane * 4 + 1], q1);
    atomicAdd(&ls[lane * 4 + 2], s2); atomicAdd(&lq[lane * 4 + 2], q2);
    atomicAdd(&ls[lane * 4 + 3], s3); atomicAdd(&lq[lane * 4 + 3], q3);
    __syncthreads();
    atomicAdd(&stats[threadIdx.x], ls[threadIdx.x]);
    atomicAdd(&stats[HID + threadIdx.x], lq[threadIdx.x]);
}

// ---------------------------------------------------------------------------
// BatchNorm apply (+relu, bf16), with inline finalize from raw stats.
// ---------------------------------------------------------------------------
__global__ __launch_bounds__(256) void k_bnapply_bf(const unsigned short* __restrict__ X,
                                                    unsigned short* __restrict__ Y,
                                                    const float* __restrict__ stats,
                                                    const float* __restrict__ gamma,
                                                    const float* __restrict__ beta) {
    int i = blockIdx.x * 256 + threadIdx.x;  // over N*32 ushort8 groups (exact)
    int ch8 = (i & 31) * 8;
    ushort8v v = *(const ushort8v*)(X + (size_t)i * 8);
    ushort8v o;
#pragma unroll
    for (int k = 0; k < 8; ++k) {
        float sc, sh;
        bn_scsh(stats, gamma, beta, ch8 + k, sc, sh);
        float f = bf2f((unsigned short)v[k]);
        o[k] = f2bf(fmaxf(f * sc + sh, 0.f));
    }
    *(ushort8v*)(Y + (size_t)i * 8) = o;
}

// ---------------------------------------------------------------------------
// Head: optional fused BN (stats != null) then logits = v @ W(256x2) + b,
// log_softmax. One wave per row.
// ---------------------------------------------------------------------------
__global__ __launch_bounds__(256) void k_head_bf(const unsigned short* __restrict__ H,
                                                 const float* __restrict__ stats,
                                                 const float* __restrict__ gamma,
                                                 const float* __restrict__ beta,
                                                 const float* __restrict__ W,
                                                 const float* __restrict__ b,
                                                 float* __restrict__ outp) {
    int wave = (blockIdx.x * 256 + threadIdx.x) >> 6;
    int lane = threadIdx.x & 63;
    if (wave >= N_NODES) return;
    ushort4 h4 = ((const ushort4*)(H + (size_t)wave * HID))[lane];
    float h0 = bf2f(h4.x), h1 = bf2f(h4.y), h2 = bf2f(h4.z), h3 = bf2f(h4.w);
    if (stats) {
        int ch = lane * 4;
        float sc, sh;
        bn_scsh(stats, gamma, beta, ch + 0, sc, sh); h0 = fmaxf(h0 * sc + sh, 0.f);
        bn_scsh(stats, gamma, beta, ch + 1, sc, sh); h1 = fmaxf(h1 * sc + sh, 0.f);
        bn_scsh(stats, gamma, beta, ch + 2, sc, sh); h2 = fmaxf(h2 * sc + sh, 0.f);
        bn_scsh(stats, gamma, beta, ch + 3, sc, sh); h3 = fmaxf(h3 * sc + sh, 0.f);
    }
    const float2* W2 = (const float2*)W;
    float2 w0 = W2[lane * 4 + 0], w1 = W2[lane * 4 + 1];
    float2 w2 = W2[lane * 4 + 2], w3 = W2[lane * 4 + 3];
    float p0 = h0 * w0.x + h1 * w1.x + h2 * w2.x + h3 * w3.x;
    float p1 = h0 * w0.y + h1 * w1.y + h2 * w2.y + h3 * w3.y;
    for (int off = 32; off > 0; off >>= 1) {
        p0 += __shfl_down(p0, off);
        p1 += __shfl_down(p1, off);
    }
    if (lane == 0) {
        float z0 = p0 + b[0], z1 = p1 + b[1];
        float m = fmaxf(z0, z1);
        float lse = m + logf(expf(z0 - m) + expf(z1 - m));
        outp[(size_t)wave * 2 + 0] = z0 - lse;
        outp[(size_t)wave * 2 + 1] = z1 - lse;
    }
}

// ---------------------------------------------------------------------------
extern "C" void kernel_launch(void* const* d_in, const int* in_sizes, int n_in,
                              void* d_out, int out_size, void* d_ws, size_t ws_size,
                              hipStream_t stream) {
    const float* x       = (const float*)d_in[0];      // N x 512
    const int*   ei      = (const int*)d_in[1];        // 2 x E (rows, cols)
    const float* conv_w0 = (const float*)d_in[2];      // 512 x 256
    const float* conv_ws = (const float*)d_in[3];      // 2 x 256 x 256
    const float* bn_g    = (const float*)d_in[5];
    const float* bn_b    = (const float*)d_in[6];
    const float* fcg_w0  = (const float*)d_in[7];      // 256 x 256
    const float* fcg_ws  = (const float*)d_in[8];      // 2 x 512 x 256
    const float* bng_g   = (const float*)d_in[10];
    const float* bng_b   = (const float*)d_in[11];
    const float* fcl_w   = (const float*)d_in[12];     // 3 x 256 x 256
    const float* bnl_g   = (const float*)d_in[14];
    const float* bnl_b   = (const float*)d_in[15];
    const float* outg_w  = (const float*)d_in[16];     // 256 x 2
    const float* outg_b  = (const float*)d_in[17];
    const float* outl_w  = (const float*)d_in[18];     // 3 x 256 x 2
    const float* outl_b  = (const float*)d_in[19];     // 3 x 2
    float* out = (float*)d_out;                        // (4, N, 2)

    const int* rows = ei;
    const int* cols = ei + E_EDGES;

    // workspace carve
    char* ws = (char*)d_ws;
    size_t off = 0;
    auto carve = [&](size_t bytes) -> void* {
        void* p = ws + off;
        off = (off + bytes + 255) & ~(size_t)255;
        return p;
    };
    const size_t ACT = (size_t)N_NODES * HID * 2;  // 25.6 MB bf16 activation
    unsigned short* xbf = (unsigned short*)carve((size_t)N_NODES * 512 * 2);
    unsigned short* tG  = (unsigned short*)carve(ACT);  // GEMM out
    unsigned short* tA  = (unsigned short*)carve(ACT);  // aggregate out
    unsigned short* hbf = (unsigned short*)carve(ACT);  // h_gcn
    unsigned short* g1  = (unsigned short*)carve(ACT);  // hg ping
    unsigned short* g2  = (unsigned short*)carve(ACT);  // hg pong
    unsigned short* wt_conv0 = (unsigned short*)carve(256 * 512 * 2);
    unsigned short* wt_conv1 = (unsigned short*)carve(256 * 256 * 2);
    unsigned short* wt_conv2 = (unsigned short*)carve(256 * 256 * 2);
    unsigned short* wt_fcg0  = (unsigned short*)carve(256 * 256 * 2);
    unsigned short* wt_fcgs0 = (unsigned short*)carve(256 * 512 * 2);
    unsigned short* wt_fcgs1 = (unsigned short*)carve(256 * 512 * 2);
    unsigned short* wt_fcl0  = (unsigned short*)carve(256 * 256 * 2);
    unsigned short* wt_fcl1  = (unsigned short*)carve(256 * 256 * 2);
    unsigned short* wt_fcl2  = (unsigned short*)carve(256 * 256 * 2);
    int*   deg    = (int*)carve(2 * 50048 * 4);  // deg + cursor (one memset)
    int*   cursor = deg + 50048;
    int*   rowptr = (int*)carve((size_t)(N_NODES + 1) * 4);
    float* dinv   = (float*)carve((size_t)N_NODES * 4);
    int*   colidx = (int*)carve((size_t)E_EDGES * 4);
    float* stats_all = (float*)carve(9 * 2 * HID * 4);  // 9 layers x (sum,sumsq)
    (void)off; (void)ws_size; (void)in_sizes; (void)n_in; (void)out_size;

    // --- graph prep + stat zeroing ---
    hipMemsetAsync(deg, 0, 2 * 50048 * 4, stream);
    hipMemsetAsync(stats_all, 0, 9 * 2 * HID * 4, stream);
    k_deg<<<E_EDGES / 256, 256, 0, stream>>>(rows, deg);
    k_dinv<<<(N_NODES + 255) / 256, 256, 0, stream>>>(deg, dinv);
    k_scan<<<1, 1024, 0, stream>>>(deg, rowptr);
    k_fill<<<E_EDGES / 256, 256, 0, stream>>>(rows, cols, rowptr, cursor, colidx);

    // --- dtype prep ---
    k_f2bf_vec<<<(N_NODES * 512 / 4 + 255) / 256, 256, 0, stream>>>(x, xbf, N_NODES * 512 / 4);
    k_wt<<<(512 * 256 + 255) / 256, 256, 0, stream>>>(conv_w0, wt_conv0, 512);
    k_wt<<<(256 * 256 + 255) / 256, 256, 0, stream>>>(conv_ws, wt_conv1, 256);
    k_wt<<<(256 * 256 + 255) / 256, 256, 0, stream>>>(conv_ws + 65536, wt_conv2, 256);
    k_wt<<<(256 * 256 + 255) / 256, 256, 0, stream>>>(fcg_w0, wt_fcg0, 256);
    k_wt<<<(512 * 256 + 255) / 256, 256, 0, stream>>>(fcg_ws, wt_fcgs0, 512);
    k_wt<<<(512 * 256 + 255) / 256, 256, 0, stream>>>(fcg_ws + 131072, wt_fcgs1, 512);
    k_wt<<<(256 * 256 + 255) / 256, 256, 0, stream>>>(fcl_w, wt_fcl0, 256);
    k_wt<<<(256 * 256 + 255) / 256, 256, 0, stream>>>(fcl_w + 65536, wt_fcl1, 256);
    k_wt<<<(256 * 256 + 255) / 256, 256, 0, stream>>>(fcl_w + 131072, wt_fcl2, 256);

    dim3 ggrid((N_NODES + 127) / 128, 2);
    auto gemm = [&](const unsigned short* A0, int lda0,
                    const unsigned short* A1, int lda1, int K0, int K,
                    const unsigned short* Bt, unsigned short* C,
                    const float* rs, float* st) {
        k_gemm_mfma<<<ggrid, 256, 0, stream>>>(A0, lda0, A1, lda1, K0, K, Bt, C, rs, st);
    };
    auto bnapply = [&](float* st, const unsigned short* X, unsigned short* Y,
                       const float* gamma, const float* beta) {
        k_bnapply_bf<<<N_NODES * 32 / 256, 256, 0, stream>>>(X, Y, st, gamma, beta);
    };
    auto agg = [&](const unsigned short* in, unsigned short* outb, float* st) {
        k_aggregate_bf<<<782, 256, 0, stream>>>(in, outb, rowptr, colidx, dinv, st);
    };
    float* st;

    // --- GCN layer 0 (K=512) ---
    st = stats_all + 0 * 512;
    gemm(xbf, 512, nullptr, 0, 512, 512, wt_conv0, tG, dinv, nullptr);
    agg(tG, tA, st);
    bnapply(st, tA, g1, bn_g + 0, bn_b + 0);        // h1
    // --- GCN layer 1 ---
    st = stats_all + 1 * 512;
    gemm(g1, 256, nullptr, 0, 256, 256, wt_conv1, tG, dinv, nullptr);
    agg(tG, tA, st);
    bnapply(st, tA, g2, bn_g + 256, bn_b + 256);    // h2
    // --- GCN layer 2 ---
    st = stats_all + 2 * 512;
    gemm(g2, 256, nullptr, 0, 256, 256, wt_conv2, tG, dinv, nullptr);
    agg(tG, tA, st);
    bnapply(st, tA, hbf, bn_g + 512, bn_b + 512);   // h_gcn

    // --- global path level 0 ---
    st = stats_all + 3 * 512;
    gemm(hbf, 256, nullptr, 0, 256, 256, wt_fcg0, tG, nullptr, st);
    bnapply(st, tG, g1, bng_g + 0, bng_b + 0);      // hg0
    // local head 0 (BN fused into head)
    st = stats_all + 4 * 512;
    gemm(g1, 256, nullptr, 0, 256, 256, wt_fcl0, tG, nullptr, st);
    k_head_bf<<<N_NODES / 4, 256, 0, stream>>>(tG, st, bnl_g + 0, bnl_b + 0,
                                               outl_w, outl_b,
                                               out + (size_t)1 * N_NODES * 2);
    // --- level 1: xg1 = concat(hg0, h) @ fcg_ws[0]  (dual-A, K=512) ---
    st = stats_all + 5 * 512;
    gemm(g1, 256, hbf, 256, 256, 512, wt_fcgs0, tG, nullptr, st);
    bnapply(st, tG, g2, bng_g + 256, bng_b + 256);  // hg1
    // local head 1 (BN fused into head)
    st = stats_all + 6 * 512;
    gemm(g2, 256, nullptr, 0, 256, 256, wt_fcl1, tG, nullptr, st);
    k_head_bf<<<N_NODES / 4, 256, 0, stream>>>(tG, st, bnl_g + 256, bnl_b + 256,
                                               outl_w + 512, outl_b + 2,
                                               out + (size_t)2 * N_NODES * 2);
    // --- level 2: xg2 = concat(hg1, h) @ fcg_ws[1] ---
    st = stats_all + 7 * 512;
    gemm(g2, 256, hbf, 256, 256, 512, wt_fcgs1, tG, nullptr, st);
    bnapply(st, tG, g1, bng_g + 512, bng_b + 512);  // hg2
    // local head 2 (BN fused into head)
    st = stats_all + 8 * 512;
    gemm(g1, 256, nullptr, 0, 256, 256, wt_fcl2, tG, nullptr, st);
    k_head_bf<<<N_NODES / 4, 256, 0, stream>>>(tG, st, bnl_g + 512, bnl_b + 512,
                                               outl_w + 1024, outl_b + 4,
                                               out + (size_t)3 * N_NODES * 2);
    // global head (og) from hg2 (already BN-applied)
    k_head_bf<<<N_NODES / 4, 256, 0, stream>>>(g1, nullptr, nullptr, nullptr,
                                               outg_w, outg_b, out);
}